// Round 1
// baseline (157.800 us; speedup 1.0000x reference)
//
#include <hip/hip_runtime.h>
#include <math.h>

#define LENGTH 500
#define NTHREADS 512

__global__ __launch_bounds__(NTHREADS) void bold_scan_kernel(
    const float* __restrict__ sigma_p, const float* __restrict__ mu_p,
    const float* __restrict__ lamb_p,  const float* __restrict__ beta_p,
    const float* __restrict__ psi_p,   const float* __restrict__ phi_p,
    const float* __restrict__ chi_p,   const float* __restrict__ noise,
    float* __restrict__ out)
{
    __shared__ float ns[LENGTH];   // staged noise
    __shared__ float ys[LENGTH];   // BOLD series
    __shared__ float red[NTHREADS / 64];
    __shared__ float bc[2];        // broadcast: [0]=mean, [1]=1/std

    const int tid  = threadIdx.x;
    const int lane = tid & 63;
    const int wid  = tid >> 6;

    // ---- stage noise into LDS (coalesced, parallel) ----
    if (tid < LENGTH) ns[tid] = noise[tid];
    __syncthreads();

    // ---- serial 500-step Euler integration on thread 0 ----
    if (tid == 0) {
        const float sigma = sigma_p[0];
        const float mu    = mu_p[0];
        const float lamb  = lamb_p[0];
        const float beta  = beta_p[0];
        const float psi   = psi_p[0];
        const float phi   = phi_p[0];
        const float chi   = chi_p[0];

        const float dt    = 0.1f;
        const float sqdt  = sqrtf(dt);
        const float k1    = 7.0f * beta;
        const float k2    = 2.0f;
        const float k3    = 2.0f * beta - 0.2f;
        const float ichi  = 1.0f / chi;
        const float ibeta = 1.0f / beta;
        const float V0    = 0.02f;
        // (1-beta)^(1/f) == exp2( log2(1-beta) / f )
        const float l2b   = log2f(1.0f - beta);

        float z = 0.0f, s = 0.0f, f = 1.0f, v = 1.0f, q = 1.0f;

        float eps = ns[0];
        for (int i = 0; i < LENGTH; ++i) {
            // prefetch next eps; ds_read latency hides under the compute chain
            float eps_next = (i + 1 < LENGTH) ? ns[i + 1] : 0.0f;

            // neural state (uses OLD z for ds below, matching the reference)
            float dz  = sigma * z - mu * z * z * z + lamb;
            float z_n = z + dt * dz + sqdt * eps;

            // hemodynamics (alpha = 1 -> fv = v)
            float fv = v;
            float ds = z - phi * s - psi * (f - 1.0f);
            float df = s;
            float dv = (f - fv) * ichi;
            float E  = 1.0f - exp2f(l2b / f);          // oxygen extraction
            float dq = (f * E * ibeta - fv * q / v) * ichi;

            s = fmaf(dt, ds, s);
            f = fmaf(dt, df, f);
            v = fmaf(dt, dv, v);
            q = fmaf(dt, dq, q);
            z = z_n;

            float y = V0 * (k1 * (1.0f - q)
                          + k2 * (1.0f - q / v)
                          + k3 * (1.0f - v));
            ys[i] = y;
            eps = eps_next;
        }
    }
    __syncthreads();

    // ---- parallel normalization: out = y / std(y, ddof=1) ----
    float y = (tid < LENGTH) ? ys[tid] : 0.0f;

    // block reduce: sum(y)
    float sum = y;
    #pragma unroll
    for (int off = 32; off; off >>= 1) sum += __shfl_down(sum, off);
    if (lane == 0) red[wid] = sum;
    __syncthreads();
    if (tid == 0) {
        float t = 0.0f;
        #pragma unroll
        for (int w = 0; w < NTHREADS / 64; ++w) t += red[w];
        bc[0] = t / (float)LENGTH;   // mean
    }
    __syncthreads();

    const float mean = bc[0];
    float d = (tid < LENGTH) ? (y - mean) : 0.0f;
    float sq = d * d;
    #pragma unroll
    for (int off = 32; off; off >>= 1) sq += __shfl_down(sq, off);
    __syncthreads();               // red[] reuse hazard
    if (lane == 0) red[wid] = sq;
    __syncthreads();
    if (tid == 0) {
        float t = 0.0f;
        #pragma unroll
        for (int w = 0; w < NTHREADS / 64; ++w) t += red[w];
        float var = t / (float)(LENGTH - 1);   // ddof = 1
        bc[1] = 1.0f / sqrtf(var);
    }
    __syncthreads();

    if (tid < LENGTH) out[tid] = y * bc[1];
}

extern "C" void kernel_launch(void* const* d_in, const int* in_sizes, int n_in,
                              void* d_out, int out_size, void* d_ws, size_t ws_size,
                              hipStream_t stream) {
    (void)in_sizes; (void)n_in; (void)d_ws; (void)ws_size; (void)out_size;
    const float* sigma = (const float*)d_in[0];
    const float* mu    = (const float*)d_in[1];
    const float* lamb  = (const float*)d_in[2];
    const float* beta  = (const float*)d_in[3];
    const float* psi   = (const float*)d_in[4];
    const float* phi   = (const float*)d_in[5];
    const float* chi   = (const float*)d_in[6];
    const float* noise = (const float*)d_in[7];
    float* out = (float*)d_out;

    bold_scan_kernel<<<1, NTHREADS, 0, stream>>>(
        sigma, mu, lamb, beta, psi, phi, chi, noise, out);
}

// Round 4
// 94.419 us; speedup vs baseline: 1.6713x; 1.6713x over previous
//
#include <hip/hip_runtime.h>
#include <math.h>

#define LENGTH 500
#define NTHREADS 512

#if __has_builtin(__builtin_amdgcn_rcpf)
#define RCPF(x) __builtin_amdgcn_rcpf(x)
#else
#define RCPF(x) (1.0f / (x))
#endif
#if __has_builtin(__builtin_amdgcn_exp2f)
#define EXP2F(x) __builtin_amdgcn_exp2f(x)
#else
#define EXP2F(x) exp2f(x)
#endif

__global__ __launch_bounds__(NTHREADS) void bold_scan_kernel(
    const float* __restrict__ sigma_p, const float* __restrict__ mu_p,
    const float* __restrict__ lamb_p,  const float* __restrict__ beta_p,
    const float* __restrict__ psi_p,   const float* __restrict__ phi_p,
    const float* __restrict__ chi_p,   const float* __restrict__ noise,
    float* __restrict__ out)
{
    __shared__ float dadd[512];    // d_i = dt*lamb + sqdt*eps_i (padded, zero tail)
    __shared__ float ys[504];      // BOLD series (504 for float4-aligned tail write)
    __shared__ float red[NTHREADS / 64];
    __shared__ float bc[2];        // broadcast: [0]=mean, [1]=1/std

    const int tid  = threadIdx.x;
    const int lane = tid & 63;
    const int wid  = tid >> 6;

    // ---- stage d_i into LDS (parallel) ----
    {
        const float dt    = 0.1f;
        const float sqdt  = sqrtf(dt);
        const float dtl   = dt * lamb_p[0];
        float v = 0.0f;
        if (tid < LENGTH) v = fmaf(sqdt, noise[tid], dtl);
        dadd[tid] = v;             // tid in [500,512) pads zeros
    }
    __syncthreads();

    // ---- serial 500-step Euler integration on thread 0 ----
    if (tid == 0) {
        const float sigma = sigma_p[0];
        const float mu    = mu_p[0];
        const float beta  = beta_p[0];
        const float psi   = psi_p[0];
        const float phi   = phi_p[0];
        const float chi   = chi_p[0];

        const float dt     = 0.1f;
        const float k1     = 7.0f * beta;
        const float k2     = 2.0f;
        const float k3     = 2.0f * beta - 0.2f;
        const float ichi   = 1.0f / chi;
        const float dtichi = dt * ichi;
        const float cv     = 1.0f - dtichi;          // shared by v and q updates
        const float cs     = 1.0f - dt * phi;
        const float b2     = dt * psi;
        const float Aq     = dtichi / beta;
        const float V0     = 0.02f;
        const float l2b    = log2f(1.0f - beta);     // (1-beta)^(1/f) = exp2(l2b/f)
        const float dtsig  = dt * sigma;
        const float ndtmu  = -dt * mu;

        float z = 0.0f, s = 0.0f, f = 1.0f, v = 1.0f, q = 1.0f;

        // loop-carried chains per step:
        //   z: z->z2->z3->zn                       (3 dependent ops)
        //   q via f: f_{i-1}->f_i->rcp->exp2->fE->q_{i+1}  (~8 ops / 2 steps)
#define STEP(D, YREF)                                                         \
        {                                                                     \
            float zD = z + (D);                                               \
            float z2 = z * z;                                                 \
            float z3 = z2 * z;                                                \
            float e  = fmaf(dtsig, z, zD);           /* z + dt*sig*z + D */   \
            float zn = fmaf(ndtmu, z3, e);                                    \
            /* hemodynamics (old z, old s, old f, old v, old q) */            \
            float inv_f = RCPF(f);                                            \
            float T  = EXP2F(l2b * inv_f);                                    \
            float fE = f - f * T;                    /* f * E */              \
            float t1 = fmaf(-b2, f, b2);             /* dt*psi*(1-f) */       \
            float t2 = fmaf(dt, z, t1);                                       \
            float sn = fmaf(cs, s, t2);                                       \
            float fn = fmaf(dt, s, f);                                        \
            float vn = fmaf(cv, v, dtichi * f);                               \
            float qn = fmaf(cv, q, Aq * fE);         /* fv*q/v == q */        \
            z = zn; s = sn; f = fn; v = vn; q = qn;                           \
            float inv_v = RCPF(v);                                            \
            (YREF) = V0 * (k1 * (1.0f - q)                                    \
                         + k2 * (1.0f - q * inv_v)                            \
                         + k3 * (1.0f - v));                                  \
        }

        const float4* dv4 = (const float4*)dadd;
        float4 curA = dv4[0];
        float4 curB = dv4[1];
        // main loop: steps 0..495, prefetch 8 ahead (load-to-use ~1 body)
        for (int i = 0; i < 496; i += 8) {
            float4 nextA = dv4[(i >> 2) + 2];
            float4 nextB = dv4[(i >> 2) + 3];
            float4 yA, yB;
            STEP(curA.x, yA.x) STEP(curA.y, yA.y)
            STEP(curA.z, yA.z) STEP(curA.w, yA.w)
            STEP(curB.x, yB.x) STEP(curB.y, yB.y)
            STEP(curB.z, yB.z) STEP(curB.w, yB.w)
            ((float4*)ys)[(i >> 2)]     = yA;
            ((float4*)ys)[(i >> 2) + 1] = yB;
            curA = nextA; curB = nextB;
        }
        // tail: steps 496..499 (curA holds dadd[496..499])
        {
            float4 yA;
            STEP(curA.x, yA.x) STEP(curA.y, yA.y)
            STEP(curA.z, yA.z) STEP(curA.w, yA.w)
            ((float4*)ys)[124] = yA;
        }
#undef STEP
    }
    __syncthreads();

    // ---- parallel normalization: out = y / std(y, ddof=1) ----
    float y = (tid < LENGTH) ? ys[tid] : 0.0f;

    float sum = y;
    #pragma unroll
    for (int off = 32; off; off >>= 1) sum += __shfl_down(sum, off);
    if (lane == 0) red[wid] = sum;
    __syncthreads();
    if (tid == 0) {
        float t = 0.0f;
        #pragma unroll
        for (int w = 0; w < NTHREADS / 64; ++w) t += red[w];
        bc[0] = t / (float)LENGTH;   // mean
    }
    __syncthreads();

    const float mean = bc[0];
    float d = (tid < LENGTH) ? (y - mean) : 0.0f;
    float sq = d * d;
    #pragma unroll
    for (int off = 32; off; off >>= 1) sq += __shfl_down(sq, off);
    __syncthreads();               // red[] reuse hazard
    if (lane == 0) red[wid] = sq;
    __syncthreads();
    if (tid == 0) {
        float t = 0.0f;
        #pragma unroll
        for (int w = 0; w < NTHREADS / 64; ++w) t += red[w];
        float var = t / (float)(LENGTH - 1);   // ddof = 1
        bc[1] = 1.0f / sqrtf(var);
    }
    __syncthreads();

    if (tid < LENGTH) out[tid] = y * bc[1];
}

extern "C" void kernel_launch(void* const* d_in, const int* in_sizes, int n_in,
                              void* d_out, int out_size, void* d_ws, size_t ws_size,
                              hipStream_t stream) {
    (void)in_sizes; (void)n_in; (void)d_ws; (void)ws_size; (void)out_size;
    const float* sigma = (const float*)d_in[0];
    const float* mu    = (const float*)d_in[1];
    const float* lamb  = (const float*)d_in[2];
    const float* beta  = (const float*)d_in[3];
    const float* psi   = (const float*)d_in[4];
    const float* phi   = (const float*)d_in[5];
    const float* chi   = (const float*)d_in[6];
    const float* noise = (const float*)d_in[7];
    float* out = (float*)d_out;

    bold_scan_kernel<<<1, NTHREADS, 0, stream>>>(
        sigma, mu, lamb, beta, psi, phi, chi, noise, out);
}

// Round 11
// 90.670 us; speedup vs baseline: 1.7404x; 1.0413x over previous
//
#include <hip/hip_runtime.h>
#include <math.h>

#define LENGTH 500
#define NTHREADS 512

#if __has_builtin(__builtin_amdgcn_rcpf)
#define RCPF(x) __builtin_amdgcn_rcpf(x)
#else
#define RCPF(x) (1.0f / (x))
#endif
#if __has_builtin(__builtin_amdgcn_exp2f)
#define EXP2F(x) __builtin_amdgcn_exp2f(x)
#else
#define EXP2F(x) exp2f(x)
#endif

__global__ __launch_bounds__(NTHREADS) void bold_scan_kernel(
    const float* __restrict__ sigma_p, const float* __restrict__ mu_p,
    const float* __restrict__ lamb_p,  const float* __restrict__ beta_p,
    const float* __restrict__ psi_p,   const float* __restrict__ phi_p,
    const float* __restrict__ chi_p,   const float* __restrict__ noise,
    float* __restrict__ out)
{
    __shared__ float  dadd[512];   // d_i = dt*lamb + sqdt*eps_i (padded, zero tail)
    __shared__ float4 qs4[125];    // q_n series, float4-batched
    __shared__ float4 vs4[125];    // v_n series
    __shared__ float  red[NTHREADS / 64];
    __shared__ float  bc[2];       // broadcast: [0]=mean, [1]=1/std

    const int tid  = threadIdx.x;
    const int lane = tid & 63;
    const int wid  = tid >> 6;

    // ---- stage d_i into LDS (parallel) ----
    {
        const float dt   = 0.1f;
        const float sqdt = sqrtf(dt);
        const float dtl  = dt * lamb_p[0];
        float d = 0.0f;
        if (tid < LENGTH) d = fmaf(sqdt, noise[tid], dtl);
        dadd[tid] = d;             // tid in [500,512) pads zeros
    }
    __syncthreads();

    // ---- serial 500-step Euler integration on thread 0 ----
    // Only the recurrences live here; the elementwise BOLD output y(q,v)
    // is offloaded to the parallel epilogue (saves ~9 ops/step on the
    // issue-bound single wave).
    if (tid == 0) {
        const float sigma = sigma_p[0];
        const float mu    = mu_p[0];
        const float beta  = beta_p[0];
        const float psi   = psi_p[0];
        const float phi   = phi_p[0];
        const float chi   = chi_p[0];

        const float dt     = 0.1f;
        const float ichi   = 1.0f / chi;
        const float dtichi = dt * ichi;
        const float cv     = 1.0f - dtichi;          // shared by v and q updates
        const float cs     = 1.0f - dt * phi;
        const float b2     = dt * psi;
        const float Aq     = dtichi / beta;
        const float l2b    = log2f(1.0f - beta);     // (1-beta)^(1/f) = exp2(l2b/f)
        const float dtsig  = dt * sigma;
        const float ndtmu  = -dt * mu;

        float z = 0.0f, s = 0.0f, f = 1.0f, v = 1.0f, q = 1.0f;

        // loop-carried chains per step:
        //   z: z->z2->z3->zn                    (3 dependent ops, ~14 cy)
        //   f->rcp->exp2->fE->q                 (parallel branch, 1 step of slack)
        // ~16 VALU ops/step => issue-bound ~32 cy/step on a single wave.
#define STEP(D, QREF, VREF)                                                   \
        {                                                                     \
            float zD = z + (D);                                               \
            float z2 = z * z;                                                 \
            float z3 = z2 * z;                                                \
            float e  = fmaf(dtsig, z, zD);           /* z + dt*sig*z + D */   \
            float zn = fmaf(ndtmu, z3, e);                                    \
            float inv_f = RCPF(f);                                            \
            float T  = EXP2F(l2b * inv_f);                                    \
            float fE = fmaf(-T, f, f);               /* f * E */              \
            float t1 = fmaf(-b2, f, b2);             /* dt*psi*(1-f) */       \
            float t2 = fmaf(dt, z, t1);                                       \
            float sn = fmaf(cs, s, t2);                                       \
            float fn = fmaf(dt, s, f);                                        \
            float vn = fmaf(dtichi, f, cv * v);                               \
            float qn = fmaf(cv, q, Aq * fE);         /* fv*q/v == q */        \
            z = zn; s = sn; f = fn; v = vn; q = qn;                           \
            (QREF) = q; (VREF) = v;                                           \
        }

        const float4* dv4 = (const float4*)dadd;
        float4 curA = dv4[0];
        float4 curB = dv4[1];
        // main loop: steps 0..495, noise prefetched one 8-step body ahead
        for (int i = 0; i < 496; i += 8) {
            float4 nextA = dv4[(i >> 2) + 2];
            float4 nextB = dv4[(i >> 2) + 3];
            float4 qA, vA, qB, vB;
            STEP(curA.x, qA.x, vA.x) STEP(curA.y, qA.y, vA.y)
            STEP(curA.z, qA.z, vA.z) STEP(curA.w, qA.w, vA.w)
            qs4[(i >> 2)]     = qA;  vs4[(i >> 2)]     = vA;
            STEP(curB.x, qB.x, vB.x) STEP(curB.y, qB.y, vB.y)
            STEP(curB.z, qB.z, vB.z) STEP(curB.w, qB.w, vB.w)
            qs4[(i >> 2) + 1] = qB;  vs4[(i >> 2) + 1] = vB;
            curA = nextA; curB = nextB;
        }
        // tail: steps 496..499 (curA holds dadd[496..499])
        {
            float4 qA, vA;
            STEP(curA.x, qA.x, vA.x) STEP(curA.y, qA.y, vA.y)
            STEP(curA.z, qA.z, vA.z) STEP(curA.w, qA.w, vA.w)
            qs4[124] = qA;  vs4[124] = vA;
        }
#undef STEP
    }
    __syncthreads();

    // ---- parallel epilogue: y = V0*(k1(1-q)+k2(1-q/v)+k3(1-v)); out = y/std ----
    float y = 0.0f;
    {
        const float beta = beta_p[0];
        const float k1   = 7.0f * beta;
        const float k2   = 2.0f;
        const float k3   = 2.0f * beta - 0.2f;
        const float V0   = 0.02f;
        if (tid < LENGTH) {
            float q = ((const float*)qs4)[tid];
            float v = ((const float*)vs4)[tid];
            y = V0 * (k1 * (1.0f - q)
                    + k2 * (1.0f - q * RCPF(v))
                    + k3 * (1.0f - v));
        }
    }

    float sum = y;
    #pragma unroll
    for (int off = 32; off; off >>= 1) sum += __shfl_down(sum, off);
    if (lane == 0) red[wid] = sum;
    __syncthreads();
    if (tid == 0) {
        float t = 0.0f;
        #pragma unroll
        for (int w = 0; w < NTHREADS / 64; ++w) t += red[w];
        bc[0] = t / (float)LENGTH;   // mean
    }
    __syncthreads();

    const float mean = bc[0];
    float d = (tid < LENGTH) ? (y - mean) : 0.0f;
    float sq = d * d;
    #pragma unroll
    for (int off = 32; off; off >>= 1) sq += __shfl_down(sq, off);
    __syncthreads();               // red[] reuse hazard
    if (lane == 0) red[wid] = sq;
    __syncthreads();
    if (tid == 0) {
        float t = 0.0f;
        #pragma unroll
        for (int w = 0; w < NTHREADS / 64; ++w) t += red[w];
        float var = t / (float)(LENGTH - 1);   // ddof = 1
        bc[1] = 1.0f / sqrtf(var);
    }
    __syncthreads();

    if (tid < LENGTH) out[tid] = y * bc[1];
}

extern "C" void kernel_launch(void* const* d_in, const int* in_sizes, int n_in,
                              void* d_out, int out_size, void* d_ws, size_t ws_size,
                              hipStream_t stream) {
    (void)in_sizes; (void)n_in; (void)d_ws; (void)ws_size; (void)out_size;
    const float* sigma = (const float*)d_in[0];
    const float* mu    = (const float*)d_in[1];
    const float* lamb  = (const float*)d_in[2];
    const float* beta  = (const float*)d_in[3];
    const float* psi   = (const float*)d_in[4];
    const float* phi   = (const float*)d_in[5];
    const float* chi   = (const float*)d_in[6];
    const float* noise = (const float*)d_in[7];
    float* out = (float*)d_out;

    bold_scan_kernel<<<1, NTHREADS, 0, stream>>>(
        sigma, mu, lamb, beta, psi, phi, chi, noise, out);
}

// Round 15
// 78.812 us; speedup vs baseline: 2.0022x; 1.1505x over previous
//
#include <hip/hip_runtime.h>
#include <math.h>

#define LENGTH 500
#define NTHREADS 512

#if __has_builtin(__builtin_amdgcn_rcpf)
#define RCPF(x) __builtin_amdgcn_rcpf(x)
#else
#define RCPF(x) (1.0f / (x))
#endif
#if __has_builtin(__builtin_amdgcn_exp2f)
#define EXP2F(x) __builtin_amdgcn_exp2f(x)
#else
#define EXP2F(x) exp2f(x)
#endif

__global__ __launch_bounds__(NTHREADS) void bold_scan_kernel(
    const float* __restrict__ sigma_p, const float* __restrict__ mu_p,
    const float* __restrict__ lamb_p,  const float* __restrict__ beta_p,
    const float* __restrict__ psi_p,   const float* __restrict__ phi_p,
    const float* __restrict__ chi_p,   const float* __restrict__ noise,
    float* __restrict__ out)
{
    __shared__ float dadd[512];    // d_i = dt*lamb + sqdt*eps_i (zero-padded)
    __shared__ float fs[504];      // f^(i), i=0..499 (float4-batched stores)
    __shared__ float wA[8], wBv[8], wBq[8];   // per-wave scan totals
    __shared__ float pA[8], pBv[8], pBq[8];   // exclusive wave prefixes
    __shared__ float red[8];
    __shared__ float bc[2];        // [0]=mean, [1]=1/std

    const int tid  = threadIdx.x;
    const int lane = tid & 63;
    const int wid  = tid >> 6;

    // ---- stage d_i into LDS (parallel) ----
    {
        const float dt   = 0.1f;
        const float sqdt = sqrtf(dt);
        const float dtl  = dt * lamb_p[0];
        float d = 0.0f;
        if (tid < LENGTH) d = fmaf(sqdt, noise[tid], dtl);
        dadd[tid] = d;
    }
    __syncthreads();

    // ---- serial scan: ONLY z, s, f recurrences (irreducibly serial part) ----
    // v, q are constant-coeff affine recurrences driven by f -> parallel-scanned
    // in the epilogue. fE(f) is elementwise -> epilogue too.
    if (tid == 0) {
        const float sigma = sigma_p[0];
        const float mu    = mu_p[0];
        const float psi   = psi_p[0];
        const float phi   = phi_p[0];

        const float dt        = 0.1f;
        const float cs        = 1.0f - dt * phi;
        const float b2        = dt * psi;
        const float nb2       = -b2;
        const float onePdtsig = 1.0f + dt * sigma;
        const float ndtmu     = -dt * mu;

        float z = 0.0f, s = 0.0f, f = 1.0f;

        // z-chain: z->z2->c->zn (3 dependent ops); s,f hang off in 4 more fmas.
        // ~8 issued ops/step incl. staging => ~16 cy/step on a single wave.
#define STEP(D, FREF)                                                         \
        {                                                                     \
            float z2 = z * z;                                                 \
            float c  = fmaf(ndtmu, z2, onePdtsig);  /* 1+dt*sig-dt*mu*z^2 */  \
            float zn = fmaf(z, c, (D));                                       \
            float t1 = fmaf(nb2, f, b2);            /* dt*psi*(1-f) */        \
            float t2 = fmaf(dt, z, t1);                                       \
            float sn = fmaf(cs, s, t2);                                       \
            float fn = fmaf(dt, s, f);                                        \
            z = zn; s = sn; f = fn;                                           \
            (FREF) = f;                                                       \
        }

        const float4* dv4 = (const float4*)dadd;
        float4* fs4 = (float4*)fs;
        float4 curA = dv4[0];
        float4 curB = dv4[1];
        for (int i = 0; i < 496; i += 8) {
            float4 nextA = dv4[(i >> 2) + 2];
            float4 nextB = dv4[(i >> 2) + 3];
            float4 fA, fB;
            STEP(curA.x, fA.x) STEP(curA.y, fA.y)
            STEP(curA.z, fA.z) STEP(curA.w, fA.w)
            fs4[(i >> 2)] = fA;
            STEP(curB.x, fB.x) STEP(curB.y, fB.y)
            STEP(curB.z, fB.z) STEP(curB.w, fB.w)
            fs4[(i >> 2) + 1] = fB;
            curA = nextA; curB = nextB;
        }
        {   // tail steps 496..499
            float4 fA;
            STEP(curA.x, fA.x) STEP(curA.y, fA.y)
            STEP(curA.z, fA.z) STEP(curA.w, fA.w)
            fs4[124] = fA;
        }
#undef STEP
    }
    __syncthreads();

    // ---- parallel epilogue ----
    const float beta   = beta_p[0];
    const float chi    = chi_p[0];
    const float dt     = 0.1f;
    const float dtichi = dt / chi;
    const float cv     = 1.0f - dtichi;
    const float Aq     = dtichi / beta;
    const float l2b    = log2f(1.0f - beta);
    const float k1     = 7.0f * beta;
    const float k2     = 2.0f;
    const float k3     = 2.0f * beta - 0.2f;
    const float V0     = 0.02f;

    // Element t consumes f^(t-1) (the "old f" of step t); f^(-1) = 1.
    // v^(t) = cv*v^(t-1) + dtichi*f^(t-1),  q^(t) = cv*q^(t-1) + Aq*fE(f^(t-1)),
    // both with x^(-1)=1 -> inclusive affine scan; shared multiplier cv.
    float a = 1.0f, bv = 0.0f, bq = 0.0f;    // identity for tid >= LENGTH
    if (tid < LENGTH) {
        float fold = (tid == 0) ? 1.0f : fs[tid - 1];
        float invf = RCPF(fold);
        float T    = EXP2F(l2b * invf);
        float fE   = fmaf(-T, fold, fold);   // f * (1 - (1-beta)^(1/f))
        a  = cv;
        bv = dtichi * fold;
        bq = Aq * fE;
    }
    // intra-wave inclusive scan (Hillis-Steele over affine maps)
    #pragma unroll
    for (int off = 1; off < 64; off <<= 1) {
        float ap  = __shfl_up(a,  off);
        float bvp = __shfl_up(bv, off);
        float bqp = __shfl_up(bq, off);
        if (lane >= off) {
            bv = fmaf(a, bvp, bv);
            bq = fmaf(a, bqp, bq);
            a  = a * ap;
        }
    }
    if (lane == 63) { wA[wid] = a; wBv[wid] = bv; wBq[wid] = bq; }
    __syncthreads();
    if (tid == 0) {   // exclusive prefix over the 8 wave totals
        float A = 1.0f, Bv = 0.0f, Bq = 0.0f;
        #pragma unroll
        for (int w = 0; w < 8; ++w) {
            pA[w] = A; pBv[w] = Bv; pBq[w] = Bq;
            Bv = fmaf(wA[w], Bv, wBv[w]);    // P_{w+1} = G_w o P_w
            Bq = fmaf(wA[w], Bq, wBq[w]);
            A  = wA[w] * A;
        }
    }
    __syncthreads();
    // total = intra o wave-prefix; x^(t) = A_t*1 + B_t (v0 = q0 = 1)
    float At  = a * pA[wid];
    float Bvt = fmaf(a, pBv[wid], bv);
    float Bqt = fmaf(a, pBq[wid], bq);
    float v = At + Bvt;
    float q = At + Bqt;

    float y = 0.0f;
    if (tid < LENGTH) {
        y = V0 * (k1 * (1.0f - q)
                + k2 * (1.0f - q * RCPF(v))
                + k3 * (1.0f - v));
    }

    // ---- out = y / std(y, ddof=1) ----
    float sum = y;
    #pragma unroll
    for (int off = 32; off; off >>= 1) sum += __shfl_down(sum, off);
    if (lane == 0) red[wid] = sum;
    __syncthreads();
    if (tid == 0) {
        float t = 0.0f;
        #pragma unroll
        for (int w = 0; w < 8; ++w) t += red[w];
        bc[0] = t / (float)LENGTH;
    }
    __syncthreads();

    const float mean = bc[0];
    float d = (tid < LENGTH) ? (y - mean) : 0.0f;
    float sq = d * d;
    #pragma unroll
    for (int off = 32; off; off >>= 1) sq += __shfl_down(sq, off);
    __syncthreads();               // red[] reuse hazard
    if (lane == 0) red[wid] = sq;
    __syncthreads();
    if (tid == 0) {
        float t = 0.0f;
        #pragma unroll
        for (int w = 0; w < 8; ++w) t += red[w];
        float var = t / (float)(LENGTH - 1);   // ddof = 1
        bc[1] = 1.0f / sqrtf(var);
    }
    __syncthreads();

    if (tid < LENGTH) out[tid] = y * bc[1];
}

extern "C" void kernel_launch(void* const* d_in, const int* in_sizes, int n_in,
                              void* d_out, int out_size, void* d_ws, size_t ws_size,
                              hipStream_t stream) {
    (void)in_sizes; (void)n_in; (void)d_ws; (void)ws_size; (void)out_size;
    const float* sigma = (const float*)d_in[0];
    const float* mu    = (const float*)d_in[1];
    const float* lamb  = (const float*)d_in[2];
    const float* beta  = (const float*)d_in[3];
    const float* psi   = (const float*)d_in[4];
    const float* phi   = (const float*)d_in[5];
    const float* chi   = (const float*)d_in[6];
    const float* noise = (const float*)d_in[7];
    float* out = (float*)d_out;

    bold_scan_kernel<<<1, NTHREADS, 0, stream>>>(
        sigma, mu, lamb, beta, psi, phi, chi, noise, out);
}